// Round 10
// baseline (392.060 us; speedup 1.0000x reference)
//
#include <hip/hip_runtime.h>
#include <hip/hip_cooperative_groups.h>

namespace cg = cooperative_groups;

#define LL 2
#define NP 1024
#define BB 8
#define FF 128
#define HH 256
#define NE (NP*NP)
#define GT 128
#define TPTS ((GT+1)*(GT+1))

typedef __attribute__((ext_vector_type(4))) float f32x4;
typedef __attribute__((ext_vector_type(8))) short bf16x8;

__device__ __forceinline__ ushort f2bf(float f) {
  unsigned int u = __float_as_uint(f);
  return (ushort)((u + 0x7FFF + ((u >> 16) & 1)) >> 16);
}

// ---------------- pre: xT transpose (0..127) + Wfc->bf16 (128..159) + table (160..291) ----------------
__global__ __launch_bounds__(256) void pre_kernel(
    const float* __restrict__ x, const float* __restrict__ Wfc,
    const float* __restrict__ W1, const float* __restrict__ b1,
    const float* __restrict__ W2, const float* __restrict__ b2,
    ushort* __restrict__ xT, ushort* __restrict__ wfcbf, float* __restrict__ tab)
{
  __shared__ __align__(16) char smem[18432];
  int t = threadIdx.x;
  int bid = blockIdx.x;

  if (bid >= 160) {               // ---- table branch ----
    float4* spk = (float4*)smem;              // 256 float4
    float*  sred = (float*)(smem + 4096);     // 256 f32
    int q = bid - 160;
    int l = (q >= 66) ? 1 : 0;
    int pb = q - l*66;
    float wx = W1[(l*HH + t)*2 + 0];
    float wy = W1[(l*HH + t)*2 + 1];
    float bb = b1[l*HH + t];
    float w2 = W2[l*HH + t];
    spk[t] = make_float4(wx*1.44269504f, wy*1.44269504f, bb*1.44269504f, w2);
    sred[t] = w2;
    __syncthreads();
    for (int s = 128; s > 0; s >>= 1) {
      if (t < s) sred[t] += sred[t+s];
      __syncthreads();
    }
    float sw2 = sred[0];
    int p = pb*256 + t;
    if (p >= TPTS) return;
    int i = p / (GT+1), j = p % (GT+1);
    float d = i * (1.0f/GT), tt = j * (1.0f/GT);
    float accp = 0.f, acce = 0.f;
    #pragma unroll 8
    for (int k = 0; k < HH; ++k) {
      float4 c = spk[k];
      float z2 = fmaf(d, c.x, fmaf(tt, c.y, c.z));
      accp = fmaf(c.w, fmaxf(z2, 0.f), accp);
      acce = fmaf(c.w, __builtin_amdgcn_exp2f(fminf(z2, 0.f)), acce);
    }
    float s = fmaf(0.69314718f, accp, acce) - sw2 + b2[l];
    float ax = fabsf(s);
    float e2 = __builtin_amdgcn_exp2f(-2.88539008f * ax);
    float r = (1.f - e2) * __builtin_amdgcn_rcpf(1.f + e2);
    tab[p*2 + l] = (s >= 0.f) ? r : -r;
    return;
  }

  if (bid >= 128) {               // ---- Wfc convert branch ----
    int i4 = (bid - 128)*256 + t;
    float4 v = *(const float4*)(Wfc + (size_t)i4*4);
    ushort4 o;
    o.x = f2bf(v.x); o.y = f2bf(v.y); o.z = f2bf(v.z); o.w = f2bf(v.w);
    *(ushort4*)(wfcbf + (size_t)i4*4) = o;
    return;
  }

  // ---- xT transpose branch ----
  ushort (*sT)[72] = (ushort(*)[72])smem;     // [128][72]
  int b = bid >> 4;
  int m0 = (bid & 15) * 64;
  int mr = t >> 2;
  int fc = (t & 3) * 32;
  const float* src = x + ((size_t)b*NP + m0 + mr)*FF + fc;
  #pragma unroll
  for (int i = 0; i < 8; ++i) {
    float4 v = *(const float4*)(src + i*4);
    sT[fc + i*4 + 0][mr] = f2bf(v.x);
    sT[fc + i*4 + 1][mr] = f2bf(v.y);
    sT[fc + i*4 + 2][mr] = f2bf(v.z);
    sT[fc + i*4 + 3][mr] = f2bf(v.w);
  }
  __syncthreads();
  int f = t >> 1, half = t & 1;
  ushort* dst = xT + ((size_t)b*FF + f)*NP + m0 + half*32;
  #pragma unroll
  for (int q = 0; q < 4; ++q)
    *(uint4*)(dst + q*8) = *(const uint4*)&sT[f][half*32 + q*8];
}

// ---------------- edge lookup: bilinear for both layers at once ----------------
__device__ __forceinline__ void lookup2(const float* __restrict__ tab,
                                        float d, float t, float out[2])
{
  float u = d * (float)GT, vv = t * (float)GT;
  int iu = (int)u; iu = min(iu, GT-1);
  int iv = (int)vv; iv = min(iv, GT-1);
  float fu = u - iu, fv = vv - iv;
  const float* p = tab + (size_t)(iu*(GT+1) + iv)*2;
  float2 t00 = *(const float2*)(p);
  float2 t01 = *(const float2*)(p + 2);
  float2 t10 = *(const float2*)(p + (GT+1)*2);
  float2 t11 = *(const float2*)(p + (GT+2)*2);
  float m = (d > 0.f) ? 1.f : 0.f;
  float a0 = t00.x + fv*(t01.x - t00.x);
  float b0 = t10.x + fv*(t11.x - t10.x);
  out[0] = m * (a0 + fu*(b0 - a0));
  float a1 = t00.y + fv*(t01.y - t00.y);
  float b1v = t10.y + fv*(t11.y - t10.y);
  out[1] = m * (a1 + fu*(b1v - a1));
}

__global__ __launch_bounds__(256) void edge_lookup_kernel(
    const float4* __restrict__ adj2, const float* __restrict__ tab,
    ushort* __restrict__ a_bf)
{
  int e2 = blockIdx.x*256 + threadIdx.x;
  float4 v = adj2[e2];
  float r0[2], r1[2];
  lookup2(tab, v.x, v.y, r0);
  lookup2(tab, v.z, v.w, r1);
  #pragma unroll
  for (int l = 0; l < LL; ++l) {
    ushort2 o;
    o.x = f2bf(r0[l]);
    o.y = f2bf(r1[l]);
    *(ushort2*)&a_bf[(size_t)l*NE + 2*e2] = o;
  }
}

// ---------------- staging helpers (linear LDS dest + pre-swizzled source) ----------------
__device__ __forceinline__ void stage64(const ushort* __restrict__ srcrow0, int stride, int k0,
                                        ushort* dst, int w, int lane)
{
  #pragma unroll
  for (int u = 0; u < 2; ++u) {
    int o = (u*4 + w)*1024 + lane*16;
    int r = o >> 7;
    int c = (o & 127) ^ ((r & 7) << 4);
    const ushort* src = srcrow0 + (size_t)r*stride + k0 + (c >> 1);
    __builtin_amdgcn_global_load_lds(
        (const __attribute__((address_space(1))) unsigned int*)(const void*)src,
        (__attribute__((address_space(3))) unsigned int*)(void*)(dst + (u*4+w)*512),
        16, 0, 0);
  }
}

__device__ __forceinline__ void stage32(const ushort* __restrict__ srcrow0, int stride, int k0,
                                        ushort* dst, int w, int lane)
{
  int o = w*1024 + lane*16;
  int r = o >> 7;                  // 0..31
  int c = (o & 127) ^ ((r & 7) << 4);
  const ushort* src = srcrow0 + (size_t)r*stride + k0 + (c >> 1);
  __builtin_amdgcn_global_load_lds(
      (const __attribute__((address_space(1))) unsigned int*)(const void*)src,
      (__attribute__((address_space(3))) unsigned int*)(void*)(dst + w*512),
      16, 0, 0);
}

// ---------------- G1 phase: xa[n][j] = sum_m a[n][m]*xT[j][m]; 32x64 tile, BK=128 ----------------
__device__ __forceinline__ void compute32x64_bk128(const ushort* sAc, const ushort* sBc,
    int wr, int wc, int lane, f32x4 acc[2])
{
  int kb = (lane >> 4) * 16;
  #pragma unroll
  for (int ks = 0; ks < 4; ++ks) {
    int sub = ks >> 1;
    int inb = (ks & 1)*64 + kb;
    int rA = wr*16 + (lane & 15);
    int offA = (rA*128 + inb) ^ ((rA & 7) << 4);
    bf16x8 af = *(const bf16x8*)((const char*)sAc + sub*4096 + offA);
    #pragma unroll
    for (int nj = 0; nj < 2; ++nj) {
      int rB = wc*32 + nj*16 + (lane & 15);
      int offB = (rB*128 + inb) ^ ((rB & 7) << 4);
      bf16x8 bg = *(const bf16x8*)((const char*)sBc + sub*8192 + offB);
      acc[nj] = __builtin_amdgcn_mfma_f32_16x16x32_bf16(af, bg, acc[nj], 0, 0, 0);
    }
  }
}

// Double-buffered, __syncthreads-only (correctness independent of vmem scheduling).
__device__ void g1_phase(const ushort* __restrict__ A, const ushort* __restrict__ B,
                         ushort* __restrict__ C, char* smem)
{
  ushort* sA = (ushort*)smem;            // 2 x 4096 ushorts (16KB)
  ushort* sB = (ushort*)(smem + 16384);  // 2 x 8192 ushorts (32KB)
  int tid = threadIdx.x;
  int w = tid >> 6, lane = tid & 63;
  int tm = blockIdx.x >> 4;     // 0..31
  int tj = blockIdx.x & 15;     // 0..15
  int n0 = tm*32, j0 = tj*64;
  const ushort* Ab = A + (size_t)n0*NP;
  const ushort* Bb = B + (size_t)j0*NP;
  int wr = w >> 1, wc = w & 1;
  f32x4 acc[2] = {};

  stage32(Ab, NP, 0,  sA,        w, lane);
  stage32(Ab, NP, 64, sA + 2048, w, lane);
  stage64(Bb, NP, 0,  sB,        w, lane);
  stage64(Bb, NP, 64, sB + 4096, w, lane);
  #pragma unroll
  for (int t = 0; t < 8; ++t) {
    int c = t & 1;
    __syncthreads();   // full vmcnt+lgkm drain: buf c staged; prior reads of c^1 done
    if (t + 1 < 8) {
      int k0 = (t+1)*128;
      stage32(Ab, NP, k0,      sA + (c^1)*4096,        w, lane);
      stage32(Ab, NP, k0 + 64, sA + (c^1)*4096 + 2048, w, lane);
      stage64(Bb, NP, k0,      sB + (c^1)*8192,        w, lane);
      stage64(Bb, NP, k0 + 64, sB + (c^1)*8192 + 4096, w, lane);
    }
    compute32x64_bk128(sA + c*4096, sB + c*8192, wr, wc, lane, acc);
  }

  int colb = wc*32 + (lane & 15);
  int rowb = wr*16 + ((lane >> 4) << 2);
  #pragma unroll
  for (int nj = 0; nj < 2; ++nj) {
    int j = j0 + colb + nj*16;
    #pragma unroll
    for (int i = 0; i < 4; ++i) {
      int n = n0 + rowb + i;
      C[(size_t)n*NP + j] = f2bf(acc[nj][i]);
    }
  }
}

// ---------------- fc_ln phase: fused fc-GEMM + bias + skip + LayerNorm + dual output ----------------
template<bool LAST>
__device__ void fc_ln_phase(
    const ushort* __restrict__ xa, const ushort* __restrict__ wl,
    const float* __restrict__ xin, const float* __restrict__ bias_l,
    const float* __restrict__ gamma_l, const float* __restrict__ beta_l,
    float* __restrict__ out, ushort* __restrict__ xT2, char* smem)
{
  ushort* sXA = (ushort*)smem;                        // 4KB: 2 subtiles [16][64]
  ushort* sW  = (ushort*)(smem + 4096);               // 32KB: 4 subtiles [64][64]
  float (*sY)[132] = (float(*)[132])(smem + 36864);   // [16][132] f32 (8448B)
  float (*sXB)[17] = (float(*)[17])(smem + 45312);    // [128][17] f32 (8704B)

  int b  = blockIdx.x >> 6;          // 0..7
  int n0 = (blockIdx.x & 63) * 16;
  int tid = threadIdx.x, w = tid >> 6, lane = tid & 63;

  // stage xa tile [16 n][128 k]: one 16B load per thread
  {
    int kh = tid >> 7;
    int o  = (tid & 127) * 16;
    int r  = o >> 7;                 // 0..15
    int c  = (o & 127) ^ ((r & 7) << 4);
    const ushort* src = xa + (size_t)(n0 + r)*NP + b*FF + kh*64 + (c >> 1);
    __builtin_amdgcn_global_load_lds(
        (const __attribute__((address_space(1))) unsigned int*)(const void*)src,
        (__attribute__((address_space(3))) unsigned int*)(void*)(sXA + w*512),
        16, 0, 0);
  }
  // stage Wfc [128 g][128 k] (4 subtiles, 8192B stride)
  #pragma unroll
  for (int gr = 0; gr < 2; ++gr)
    #pragma unroll
    for (int kf = 0; kf < 2; ++kf)
      stage64(wl + gr*64*FF, FF, kf*64, sW + (gr*2+kf)*4096, w, lane);

  // skip-connection + bias loads (overlap with staging)
  int col = lane & 15;
  int rowb = (lane >> 4) * 4;
  float xr[2][4];
  float bv[2];
  #pragma unroll
  for (int nj = 0; nj < 2; ++nj) {
    int g = w*32 + nj*16 + col;
    bv[nj] = bias_l[g];
    #pragma unroll
    for (int i = 0; i < 4; ++i)
      xr[nj][i] = xin[((size_t)b*NP + n0 + rowb + i)*FF + g];
  }
  __syncthreads();

  // MFMA: C[16 n][128 g], K=128
  f32x4 acc[2] = {};
  #pragma unroll
  for (int ks = 0; ks < 4; ++ks) {
    int inb = (ks & 1)*64 + (lane >> 4)*16;
    int r = lane & 15;
    int offA = (r*128 + inb) ^ ((r & 7) << 4);
    bf16x8 af = *(const bf16x8*)((const char*)sXA + (ks>>1)*2048 + offA);
    #pragma unroll
    for (int nj = 0; nj < 2; ++nj) {
      int gg = w*32 + nj*16 + (lane & 15);
      int gr = gg >> 6, rs = gg & 63;
      int offB = (rs*128 + inb) ^ ((rs & 7) << 4);
      bf16x8 bg = *(const bf16x8*)((const char*)sW + (gr*2 + (ks>>1))*8192 + offB);
      acc[nj] = __builtin_amdgcn_mfma_f32_16x16x32_bf16(af, bg, acc[nj], 0, 0, 0);
    }
  }

  // y -> LDS
  #pragma unroll
  for (int nj = 0; nj < 2; ++nj) {
    int g = w*32 + nj*16 + col;
    #pragma unroll
    for (int i = 0; i < 4; ++i)
      sY[rowb + i][g] = acc[nj][i] + xr[nj][i] + bv[nj];
  }
  __syncthreads();

  // LayerNorm: 16 threads per row
  int row = tid >> 4, seg = tid & 15;
  float4 v[2];
  float s = 0.f, ss = 0.f;
  #pragma unroll
  for (int q = 0; q < 2; ++q) {
    v[q] = *(const float4*)&sY[row][seg*8 + q*4];
    s  += v[q].x + v[q].y + v[q].z + v[q].w;
    ss += v[q].x*v[q].x + v[q].y*v[q].y + v[q].z*v[q].z + v[q].w*v[q].w;
  }
  #pragma unroll
  for (int o = 1; o < 16; o <<= 1) {
    s  += __shfl_xor(s, o);
    ss += __shfl_xor(ss, o);
  }
  float mean = s * (1.f/FF);
  float var  = ss * (1.f/FF) - mean*mean;
  float inv  = __builtin_amdgcn_rsqf(var + 1e-5f);
  size_t obase = ((size_t)b*NP + n0 + row)*FF + seg*8;
  float res[8];
  #pragma unroll
  for (int q = 0; q < 2; ++q) {
    float4 g4 = *(const float4*)&gamma_l[seg*8 + q*4];
    float4 b4 = *(const float4*)&beta_l[seg*8 + q*4];
    float4 o4;
    o4.x = (v[q].x - mean)*inv*g4.x + b4.x;
    o4.y = (v[q].y - mean)*inv*g4.y + b4.y;
    o4.z = (v[q].z - mean)*inv*g4.z + b4.z;
    o4.w = (v[q].w - mean)*inv*g4.w + b4.w;
    *(float4*)&out[obase + q*4] = o4;
    res[q*4+0] = o4.x; res[q*4+1] = o4.y; res[q*4+2] = o4.z; res[q*4+3] = o4.w;
  }

  if constexpr (!LAST) {
    #pragma unroll
    for (int q = 0; q < 8; ++q)
      sXB[seg*8 + q][row] = res[q];
    __syncthreads();
    int f = tid >> 1, half = tid & 1;
    unsigned w0 = (unsigned)f2bf(sXB[f][half*8+0]) | ((unsigned)f2bf(sXB[f][half*8+1])<<16);
    unsigned w1 = (unsigned)f2bf(sXB[f][half*8+2]) | ((unsigned)f2bf(sXB[f][half*8+3])<<16);
    unsigned w2 = (unsigned)f2bf(sXB[f][half*8+4]) | ((unsigned)f2bf(sXB[f][half*8+5])<<16);
    unsigned w3 = (unsigned)f2bf(sXB[f][half*8+6]) | ((unsigned)f2bf(sXB[f][half*8+7])<<16);
    ushort* dst = xT2 + ((size_t)b*FF + f)*NP + n0 + half*8;
    *(uint4*)(dst) = make_uint4(w0, w1, w2, w3);
  }
}

// ---------------- fused main chain: g1(l0) -> fc_ln(l0) -> g1(l1) -> fc_ln(l1) ----------------
__global__ __launch_bounds__(256) void main_kernel(
    const ushort* a_bf, const ushort* xT, ushort* xa, ushort* xT2,
    const ushort* wfcbf, const float* x, const float* bias,
    const float* gamma, const float* beta, float* xmid, float* out)
{
  __shared__ __align__(16) char smem[54016];
  cg::grid_group grid = cg::this_grid();

  g1_phase(a_bf, xT, xa, smem);
  __threadfence();
  grid.sync();

  fc_ln_phase<false>(xa, wfcbf, x, bias, gamma, beta, xmid, xT2, smem);
  __threadfence();
  grid.sync();

  g1_phase(a_bf + NE, xT2, xa, smem);
  __threadfence();
  grid.sync();

  fc_ln_phase<true>(xa, wfcbf + FF*FF, xmid, bias + FF, gamma + FF, beta + FF,
                    out, nullptr, smem);
}

extern "C" void kernel_launch(void* const* d_in, const int* in_sizes, int n_in,
                              void* d_out, int out_size, void* d_ws, size_t ws_size,
                              hipStream_t stream)
{
  const float* x     = (const float*)d_in[0];
  const float* adj   = (const float*)d_in[1];
  const float* W1    = (const float*)d_in[2];
  const float* b1    = (const float*)d_in[3];
  const float* W2    = (const float*)d_in[4];
  const float* b2    = (const float*)d_in[5];
  const float* Wfc   = (const float*)d_in[6];
  const float* bias  = (const float*)d_in[7];
  const float* gamma = (const float*)d_in[8];
  const float* beta  = (const float*)d_in[9];

  float* ws = (float*)d_ws;
  ushort* a_bf  = (ushort*)(ws + 0);        // 2*NE bf16
  ushort* xT    = (ushort*)(ws + 1048576);  // NE bf16
  ushort* xT2   = (ushort*)(ws + 1572864);  // NE bf16
  ushort* xa    = (ushort*)(ws + 2097152);  // NE bf16
  ushort* wfcbf = (ushort*)(ws + 2621440);  // 32768 bf16
  float*  tab   = ws + 2637824;             // TPTS*2 floats (interleaved [p][l])
  float*  xmid  = ws + 2671360;             // NE f32
  float*  outp  = (float*)d_out;

  pre_kernel<<<292, 256, 0, stream>>>(x, Wfc, W1, b1, W2, b2, xT, wfcbf, tab);
  edge_lookup_kernel<<<NE/512, 256, 0, stream>>>((const float4*)adj, tab, a_bf);

  void* args[11] = {
    (void*)&a_bf, (void*)&xT, (void*)&xa, (void*)&xT2, (void*)&wfcbf,
    (void*)&x, (void*)&bias, (void*)&gamma, (void*)&beta, (void*)&xmid, (void*)&outp
  };
  hipLaunchCooperativeKernel((void*)main_kernel, dim3(512), dim3(256), args, 0, stream);
}

// Round 12
// 67.596 us; speedup vs baseline: 5.8000x; 5.8000x over previous
//
#include <hip/hip_runtime.h>

#define LL 2
#define NP 1024
#define BB 8
#define FF 128
#define HH 256
#define NE (NP*NP)
#define GT 128
#define TPTS ((GT+1)*(GT+1))

typedef __attribute__((ext_vector_type(4))) float f32x4;
typedef __attribute__((ext_vector_type(8))) short bf16x8;

__device__ __forceinline__ ushort f2bf(float f) {
  unsigned int u = __float_as_uint(f);
  return (ushort)((u + 0x7FFF + ((u >> 16) & 1)) >> 16);
}

// ---------------- pre: xT transpose (0..127) + Wfc->bf16 (128..159) + table (160..291) ----------------
__global__ __launch_bounds__(256) void pre_kernel(
    const float* __restrict__ x, const float* __restrict__ Wfc,
    const float* __restrict__ W1, const float* __restrict__ b1,
    const float* __restrict__ W2, const float* __restrict__ b2,
    ushort* __restrict__ xT, ushort* __restrict__ wfcbf, float* __restrict__ tab)
{
  __shared__ __align__(16) char smem[18432];
  int t = threadIdx.x;
  int bid = blockIdx.x;

  if (bid >= 160) {               // ---- table branch ----
    float4* spk = (float4*)smem;              // 256 float4
    float*  sred = (float*)(smem + 4096);     // 256 f32
    int q = bid - 160;
    int l = (q >= 66) ? 1 : 0;
    int pb = q - l*66;
    float wx = W1[(l*HH + t)*2 + 0];
    float wy = W1[(l*HH + t)*2 + 1];
    float bb = b1[l*HH + t];
    float w2 = W2[l*HH + t];
    spk[t] = make_float4(wx*1.44269504f, wy*1.44269504f, bb*1.44269504f, w2);
    sred[t] = w2;
    __syncthreads();
    for (int s = 128; s > 0; s >>= 1) {
      if (t < s) sred[t] += sred[t+s];
      __syncthreads();
    }
    float sw2 = sred[0];
    int p = pb*256 + t;
    if (p >= TPTS) return;
    int i = p / (GT+1), j = p % (GT+1);
    float d = i * (1.0f/GT), tt = j * (1.0f/GT);
    float accp = 0.f, acce = 0.f;
    #pragma unroll 8
    for (int k = 0; k < HH; ++k) {
      float4 c = spk[k];
      float z2 = fmaf(d, c.x, fmaf(tt, c.y, c.z));
      accp = fmaf(c.w, fmaxf(z2, 0.f), accp);
      acce = fmaf(c.w, __builtin_amdgcn_exp2f(fminf(z2, 0.f)), acce);
    }
    float s = fmaf(0.69314718f, accp, acce) - sw2 + b2[l];
    float ax = fabsf(s);
    float e2 = __builtin_amdgcn_exp2f(-2.88539008f * ax);
    float r = (1.f - e2) * __builtin_amdgcn_rcpf(1.f + e2);
    tab[p*2 + l] = (s >= 0.f) ? r : -r;
    return;
  }

  if (bid >= 128) {               // ---- Wfc convert branch ----
    int i4 = (bid - 128)*256 + t;
    float4 v = *(const float4*)(Wfc + (size_t)i4*4);
    ushort4 o;
    o.x = f2bf(v.x); o.y = f2bf(v.y); o.z = f2bf(v.z); o.w = f2bf(v.w);
    *(ushort4*)(wfcbf + (size_t)i4*4) = o;
    return;
  }

  // ---- xT transpose branch ----
  ushort (*sT)[72] = (ushort(*)[72])smem;     // [128][72]
  int b = bid >> 4;
  int m0 = (bid & 15) * 64;
  int mr = t >> 2;
  int fc = (t & 3) * 32;
  const float* src = x + ((size_t)b*NP + m0 + mr)*FF + fc;
  #pragma unroll
  for (int i = 0; i < 8; ++i) {
    float4 v = *(const float4*)(src + i*4);
    sT[fc + i*4 + 0][mr] = f2bf(v.x);
    sT[fc + i*4 + 1][mr] = f2bf(v.y);
    sT[fc + i*4 + 2][mr] = f2bf(v.z);
    sT[fc + i*4 + 3][mr] = f2bf(v.w);
  }
  __syncthreads();
  int f = t >> 1, half = t & 1;
  ushort* dst = xT + ((size_t)b*FF + f)*NP + m0 + half*32;
  #pragma unroll
  for (int q = 0; q < 4; ++q)
    *(uint4*)(dst + q*8) = *(const uint4*)&sT[f][half*32 + q*8];
}

// ---------------- edge lookup: bilinear for both layers at once ----------------
__device__ __forceinline__ void lookup2(const float* __restrict__ tab,
                                        float d, float t, float out[2])
{
  float u = d * (float)GT, vv = t * (float)GT;
  int iu = (int)u; iu = min(iu, GT-1);
  int iv = (int)vv; iv = min(iv, GT-1);
  float fu = u - iu, fv = vv - iv;
  const float* p = tab + (size_t)(iu*(GT+1) + iv)*2;
  float2 t00 = *(const float2*)(p);
  float2 t01 = *(const float2*)(p + 2);
  float2 t10 = *(const float2*)(p + (GT+1)*2);
  float2 t11 = *(const float2*)(p + (GT+2)*2);
  float m = (d > 0.f) ? 1.f : 0.f;
  float a0 = t00.x + fv*(t01.x - t00.x);
  float b0 = t10.x + fv*(t11.x - t10.x);
  out[0] = m * (a0 + fu*(b0 - a0));
  float a1 = t00.y + fv*(t01.y - t00.y);
  float b1v = t10.y + fv*(t11.y - t10.y);
  out[1] = m * (a1 + fu*(b1v - a1));
}

__global__ __launch_bounds__(256) void edge_lookup_kernel(
    const float4* __restrict__ adj2, const float* __restrict__ tab,
    ushort* __restrict__ a_bf)
{
  int e2 = blockIdx.x*256 + threadIdx.x;
  float4 v = adj2[e2];
  float r0[2], r1[2];
  lookup2(tab, v.x, v.y, r0);
  lookup2(tab, v.z, v.w, r1);
  #pragma unroll
  for (int l = 0; l < LL; ++l) {
    ushort2 o;
    o.x = f2bf(r0[l]);
    o.y = f2bf(r1[l]);
    *(ushort2*)&a_bf[(size_t)l*NE + 2*e2] = o;
  }
}

// ---------------- staging helpers (linear LDS dest + pre-swizzled source) ----------------
__device__ __forceinline__ void stage64(const ushort* __restrict__ srcrow0, int stride, int k0,
                                        ushort* dst, int w, int lane)
{
  #pragma unroll
  for (int u = 0; u < 2; ++u) {
    int o = (u*4 + w)*1024 + lane*16;
    int r = o >> 7;
    int c = (o & 127) ^ ((r & 7) << 4);
    const ushort* src = srcrow0 + (size_t)r*stride + k0 + (c >> 1);
    __builtin_amdgcn_global_load_lds(
        (const __attribute__((address_space(1))) unsigned int*)(const void*)src,
        (__attribute__((address_space(3))) unsigned int*)(void*)(dst + (u*4+w)*512),
        16, 0, 0);
  }
}

// stage a [16][128] bf16 tile (fc-A layout, swizzled): one 16B load per thread
__device__ __forceinline__ void stage16x128(const ushort* __restrict__ rowbase, int k0,
                                            ushort* dst, int tid)
{
  int kh = tid >> 7;
  int o  = (tid & 127) * 16;
  int r  = o >> 7;                 // 0..15
  int c  = (o & 127) ^ ((r & 7) << 4);
  const ushort* src = rowbase + (size_t)r*NP + k0 + kh*64 + (c >> 1);
  __builtin_amdgcn_global_load_lds(
      (const __attribute__((address_space(1))) unsigned int*)(const void*)src,
      (__attribute__((address_space(3))) unsigned int*)(void*)(dst + (tid>>6)*512),
      16, 0, 0);
}

// ---------------- G1v2: xa[n][b*128+f] = sum_m a[n][m]*xT[b*128+f][m] ----------------
// Block (b, n0): 16 rows x 128 cols. A staged LDS dbuf (__syncthreads-only, proven
// staging code); B fragments read per-lane from global/L2 (mechanism under test).
__global__ __launch_bounds__(256) void g1v2_kernel(
    const ushort* __restrict__ A, const ushort* __restrict__ B,
    ushort* __restrict__ C)
{
  __shared__ __align__(16) ushort sA[2][2048];  // 2 x [16][128] (4096B each)
  int tid = threadIdx.x, w = tid >> 6, lane = tid & 63;
  int b  = blockIdx.x >> 6;          // 0..7
  int n0 = (blockIdx.x & 63) * 16;
  const ushort* Arow = A + (size_t)n0*NP;
  const ushort* Bb   = B + (size_t)b*FF*NP;
  const ushort* Brow[2];
  #pragma unroll
  for (int nj = 0; nj < 2; ++nj)
    Brow[nj] = Bb + (size_t)(w*32 + nj*16 + (lane & 15))*NP + (lane >> 4)*8;

  f32x4 acc1[2] = {};
  stage16x128(Arow, 0, &sA[0][0], tid);
  #pragma unroll
  for (int t = 0; t < 8; ++t) {
    int c = t & 1;
    __syncthreads();   // full drain: buf c staged; prior reads of buf c^1 done
    if (t + 1 < 8)
      stage16x128(Arow, (t+1)*128, &sA[c^1][0], tid);
    int r = lane & 15, kb = (lane >> 4)*16;
    #pragma unroll
    for (int ks = 0; ks < 4; ++ks) {
      int inb = (ks & 1)*64 + kb;
      int offA = ((r*128 + inb) ^ ((r & 7) << 4)) + (ks >> 1)*2048;
      bf16x8 af = *(const bf16x8*)((const char*)&sA[c][0] + offA);
      #pragma unroll
      for (int nj = 0; nj < 2; ++nj) {
        bf16x8 bg = *(const bf16x8*)(Brow[nj] + t*128 + ks*32);  // per-lane global (L2)
        acc1[nj] = __builtin_amdgcn_mfma_f32_16x16x32_bf16(af, bg, acc1[nj], 0, 0, 0);
      }
    }
  }

  int colb = lane & 15;
  int rowb = (lane >> 4) * 4;
  #pragma unroll
  for (int nj = 0; nj < 2; ++nj) {
    int j = b*FF + w*32 + nj*16 + colb;
    #pragma unroll
    for (int i = 0; i < 4; ++i)
      C[(size_t)(n0 + rowb + i)*NP + j] = f2bf(acc1[nj][i]);
  }
}

// ---------------- K2: fused fc-GEMM + bias + skip + LayerNorm + dual output ----------------
// 16-row blocks, 512 blocks.  xh[n][g] = sum_k xa[n][b*128+k]*Wfc[g][k]; y = xh+xin+bias; LN.
template<bool LAST>
__global__ __launch_bounds__(256) void fc_ln_kernel(
    const ushort* __restrict__ xa, const ushort* __restrict__ wl,
    const float* __restrict__ xin, const float* __restrict__ bias_l,
    const float* __restrict__ gamma_l, const float* __restrict__ beta_l,
    float* __restrict__ out, ushort* __restrict__ xT2)
{
  __shared__ __align__(16) char smem[54016];
  ushort* sXA = (ushort*)smem;                        // 4KB: 2 subtiles [16][64] (2048B each)
  ushort* sW  = (ushort*)(smem + 4096);               // 32KB: 4 subtiles [64][64] (8192B each)
  float (*sY)[132] = (float(*)[132])(smem + 36864);   // [16][132] f32 (8448B)
  float (*sXB)[17] = (float(*)[17])(smem + 45312);    // [128][17] f32 (8704B) — no aliasing

  int b  = blockIdx.x >> 6;          // 0..7
  int n0 = (blockIdx.x & 63) * 16;
  int tid = threadIdx.x, w = tid >> 6, lane = tid & 63;

  // stage xa tile [16 n][128 k]: one 16B load per thread
  {
    int kh = tid >> 7;
    int o  = (tid & 127) * 16;
    int r  = o >> 7;                 // 0..15
    int c  = (o & 127) ^ ((r & 7) << 4);
    const ushort* src = xa + (size_t)(n0 + r)*NP + b*FF + kh*64 + (c >> 1);
    __builtin_amdgcn_global_load_lds(
        (const __attribute__((address_space(1))) unsigned int*)(const void*)src,
        (__attribute__((address_space(3))) unsigned int*)(void*)(sXA + w*512),
        16, 0, 0);
  }
  // stage Wfc [128 g][128 k] (4 subtiles, 8192B stride)
  #pragma unroll
  for (int gr = 0; gr < 2; ++gr)
    #pragma unroll
    for (int kf = 0; kf < 2; ++kf)
      stage64(wl + gr*64*FF, FF, kf*64, sW + (gr*2+kf)*4096, w, lane);

  // skip-connection + bias loads (overlap with staging)
  int col = lane & 15;
  int rowb = (lane >> 4) * 4;
  float xr[2][4];
  float bv[2];
  #pragma unroll
  for (int nj = 0; nj < 2; ++nj) {
    int g = w*32 + nj*16 + col;
    bv[nj] = bias_l[g];
    #pragma unroll
    for (int i = 0; i < 4; ++i)
      xr[nj][i] = xin[((size_t)b*NP + n0 + rowb + i)*FF + g];
  }
  __syncthreads();

  // MFMA: C[16 n][128 g], K=128
  f32x4 acc[2] = {};
  #pragma unroll
  for (int ks = 0; ks < 4; ++ks) {
    int inb = (ks & 1)*64 + (lane >> 4)*16;
    int r = lane & 15;
    int offA = (r*128 + inb) ^ ((r & 7) << 4);
    bf16x8 af = *(const bf16x8*)((const char*)sXA + (ks>>1)*2048 + offA);
    #pragma unroll
    for (int nj = 0; nj < 2; ++nj) {
      int gg = w*32 + nj*16 + (lane & 15);
      int gr = gg >> 6, rs = gg & 63;
      int offB = (rs*128 + inb) ^ ((rs & 7) << 4);
      bf16x8 bg = *(const bf16x8*)((const char*)sW + (gr*2 + (ks>>1))*8192 + offB);
      acc[nj] = __builtin_amdgcn_mfma_f32_16x16x32_bf16(af, bg, acc[nj], 0, 0, 0);
    }
  }

  // y -> LDS
  #pragma unroll
  for (int nj = 0; nj < 2; ++nj) {
    int g = w*32 + nj*16 + col;
    #pragma unroll
    for (int i = 0; i < 4; ++i)
      sY[rowb + i][g] = acc[nj][i] + xr[nj][i] + bv[nj];
  }
  __syncthreads();

  // LayerNorm: 16 threads per row
  int row = tid >> 4, seg = tid & 15;
  float4 v[2];
  float s = 0.f, ss = 0.f;
  #pragma unroll
  for (int q = 0; q < 2; ++q) {
    v[q] = *(const float4*)&sY[row][seg*8 + q*4];
    s  += v[q].x + v[q].y + v[q].z + v[q].w;
    ss += v[q].x*v[q].x + v[q].y*v[q].y + v[q].z*v[q].z + v[q].w*v[q].w;
  }
  #pragma unroll
  for (int o = 1; o < 16; o <<= 1) {
    s  += __shfl_xor(s, o);
    ss += __shfl_xor(ss, o);
  }
  float mean = s * (1.f/FF);
  float var  = ss * (1.f/FF) - mean*mean;
  float inv  = __builtin_amdgcn_rsqf(var + 1e-5f);
  size_t obase = ((size_t)b*NP + n0 + row)*FF + seg*8;
  float res[8];
  #pragma unroll
  for (int q = 0; q < 2; ++q) {
    float4 g4 = *(const float4*)&gamma_l[seg*8 + q*4];
    float4 b4 = *(const float4*)&beta_l[seg*8 + q*4];
    float4 o4;
    o4.x = (v[q].x - mean)*inv*g4.x + b4.x;
    o4.y = (v[q].y - mean)*inv*g4.y + b4.y;
    o4.z = (v[q].z - mean)*inv*g4.z + b4.z;
    o4.w = (v[q].w - mean)*inv*g4.w + b4.w;
    *(float4*)&out[obase + q*4] = o4;
    res[q*4+0] = o4.x; res[q*4+1] = o4.y; res[q*4+2] = o4.z; res[q*4+3] = o4.w;
  }

  if constexpr (!LAST) {
    #pragma unroll
    for (int q = 0; q < 8; ++q)
      sXB[seg*8 + q][row] = res[q];
    __syncthreads();
    int f = tid >> 1, half = tid & 1;
    unsigned w0 = (unsigned)f2bf(sXB[f][half*8+0]) | ((unsigned)f2bf(sXB[f][half*8+1])<<16);
    unsigned w1 = (unsigned)f2bf(sXB[f][half*8+2]) | ((unsigned)f2bf(sXB[f][half*8+3])<<16);
    unsigned w2 = (unsigned)f2bf(sXB[f][half*8+4]) | ((unsigned)f2bf(sXB[f][half*8+5])<<16);
    unsigned w3 = (unsigned)f2bf(sXB[f][half*8+6]) | ((unsigned)f2bf(sXB[f][half*8+7])<<16);
    ushort* dst = xT2 + ((size_t)b*FF + f)*NP + n0 + half*8;
    *(uint4*)(dst) = make_uint4(w0, w1, w2, w3);
  }
}

extern "C" void kernel_launch(void* const* d_in, const int* in_sizes, int n_in,
                              void* d_out, int out_size, void* d_ws, size_t ws_size,
                              hipStream_t stream)
{
  const float* x     = (const float*)d_in[0];
  const float* adj   = (const float*)d_in[1];
  const float* W1    = (const float*)d_in[2];
  const float* b1    = (const float*)d_in[3];
  const float* W2    = (const float*)d_in[4];
  const float* b2    = (const float*)d_in[5];
  const float* Wfc   = (const float*)d_in[6];
  const float* bias  = (const float*)d_in[7];
  const float* gamma = (const float*)d_in[8];
  const float* beta  = (const float*)d_in[9];

  float* ws = (float*)d_ws;
  ushort* a_bf  = (ushort*)(ws + 0);        // 2*NE bf16
  ushort* xT    = (ushort*)(ws + 1048576);  // NE bf16
  ushort* xT2   = (ushort*)(ws + 1572864);  // NE bf16
  ushort* xa    = (ushort*)(ws + 2097152);  // NE bf16
  ushort* wfcbf = (ushort*)(ws + 2621440);  // 32768 bf16
  float*  tab   = ws + 2637824;             // TPTS*2 floats (interleaved [p][l])
  float*  xmid  = ws + 2671360;             // NE f32

  pre_kernel<<<292, 256, 0, stream>>>(x, Wfc, W1, b1, W2, b2, xT, wfcbf, tab);
  edge_lookup_kernel<<<NE/512, 256, 0, stream>>>((const float4*)adj, tab, a_bf);

  // layer 0
  g1v2_kernel<<<512, 256, 0, stream>>>(a_bf, xT, xa);
  fc_ln_kernel<false><<<512, 256, 0, stream>>>(xa, wfcbf, x, bias, gamma, beta, xmid, xT2);
  // layer 1
  g1v2_kernel<<<512, 256, 0, stream>>>(a_bf + NE, xT2, xa);
  fc_ln_kernel<true><<<512, 256, 0, stream>>>(xa, wfcbf + FF*FF, xmid, bias + FF,
                                              gamma + FF, beta + FF, (float*)d_out, nullptr);
}

// Round 13
// 49.628 us; speedup vs baseline: 7.9000x; 1.3621x over previous
//
#include <hip/hip_runtime.h>

#define LL 2
#define NP 1024
#define BB 8
#define FF 128
#define HH 256
#define NE (NP*NP)
#define GT 128
#define TPTS ((GT+1)*(GT+1))

typedef __attribute__((ext_vector_type(4))) float f32x4;
typedef __attribute__((ext_vector_type(8))) short bf16x8;

__device__ __forceinline__ ushort f2bf(float f) {
  unsigned int u = __float_as_uint(f);
  return (ushort)((u + 0x7FFF + ((u >> 16) & 1)) >> 16);
}

// ---------------- pre: xT transpose (0..127) + Wfc->bf16 (128..159) + table (160..291) ----------------
__global__ __launch_bounds__(256) void pre_kernel(
    const float* __restrict__ x, const float* __restrict__ Wfc,
    const float* __restrict__ W1, const float* __restrict__ b1,
    const float* __restrict__ W2, const float* __restrict__ b2,
    ushort* __restrict__ xT, ushort* __restrict__ wfcbf, float* __restrict__ tab)
{
  __shared__ __align__(16) char smem[18432];
  int t = threadIdx.x;
  int bid = blockIdx.x;

  if (bid >= 160) {               // ---- table branch ----
    float4* spk = (float4*)smem;              // 256 float4
    float*  sred = (float*)(smem + 4096);     // 256 f32
    int q = bid - 160;
    int l = (q >= 66) ? 1 : 0;
    int pb = q - l*66;
    float wx = W1[(l*HH + t)*2 + 0];
    float wy = W1[(l*HH + t)*2 + 1];
    float bb = b1[l*HH + t];
    float w2 = W2[l*HH + t];
    spk[t] = make_float4(wx*1.44269504f, wy*1.44269504f, bb*1.44269504f, w2);
    sred[t] = w2;
    __syncthreads();
    for (int s = 128; s > 0; s >>= 1) {
      if (t < s) sred[t] += sred[t+s];
      __syncthreads();
    }
    float sw2 = sred[0];
    int p = pb*256 + t;
    if (p >= TPTS) return;
    int i = p / (GT+1), j = p % (GT+1);
    float d = i * (1.0f/GT), tt = j * (1.0f/GT);
    float accp = 0.f, acce = 0.f;
    #pragma unroll 8
    for (int k = 0; k < HH; ++k) {
      float4 c = spk[k];
      float z2 = fmaf(d, c.x, fmaf(tt, c.y, c.z));
      accp = fmaf(c.w, fmaxf(z2, 0.f), accp);
      acce = fmaf(c.w, __builtin_amdgcn_exp2f(fminf(z2, 0.f)), acce);
    }
    float s = fmaf(0.69314718f, accp, acce) - sw2 + b2[l];
    float ax = fabsf(s);
    float e2 = __builtin_amdgcn_exp2f(-2.88539008f * ax);
    float r = (1.f - e2) * __builtin_amdgcn_rcpf(1.f + e2);
    tab[p*2 + l] = (s >= 0.f) ? r : -r;
    return;
  }

  if (bid >= 128) {               // ---- Wfc convert branch ----
    int i4 = (bid - 128)*256 + t;
    float4 v = *(const float4*)(Wfc + (size_t)i4*4);
    ushort4 o;
    o.x = f2bf(v.x); o.y = f2bf(v.y); o.z = f2bf(v.z); o.w = f2bf(v.w);
    *(ushort4*)(wfcbf + (size_t)i4*4) = o;
    return;
  }

  // ---- xT transpose branch ----
  ushort (*sT)[72] = (ushort(*)[72])smem;     // [128][72]
  int b = bid >> 4;
  int m0 = (bid & 15) * 64;
  int mr = t >> 2;
  int fc = (t & 3) * 32;
  const float* src = x + ((size_t)b*NP + m0 + mr)*FF + fc;
  #pragma unroll
  for (int i = 0; i < 8; ++i) {
    float4 v = *(const float4*)(src + i*4);
    sT[fc + i*4 + 0][mr] = f2bf(v.x);
    sT[fc + i*4 + 1][mr] = f2bf(v.y);
    sT[fc + i*4 + 2][mr] = f2bf(v.z);
    sT[fc + i*4 + 3][mr] = f2bf(v.w);
  }
  __syncthreads();
  int f = t >> 1, half = t & 1;
  ushort* dst = xT + ((size_t)b*FF + f)*NP + m0 + half*32;
  #pragma unroll
  for (int q = 0; q < 4; ++q)
    *(uint4*)(dst + q*8) = *(const uint4*)&sT[f][half*32 + q*8];
}

// ---------------- edge lookup: bilinear for both layers at once ----------------
__device__ __forceinline__ void lookup2(const float* __restrict__ tab,
                                        float d, float t, float out[2])
{
  float u = d * (float)GT, vv = t * (float)GT;
  int iu = (int)u; iu = min(iu, GT-1);
  int iv = (int)vv; iv = min(iv, GT-1);
  float fu = u - iu, fv = vv - iv;
  const float* p = tab + (size_t)(iu*(GT+1) + iv)*2;
  float2 t00 = *(const float2*)(p);
  float2 t01 = *(const float2*)(p + 2);
  float2 t10 = *(const float2*)(p + (GT+1)*2);
  float2 t11 = *(const float2*)(p + (GT+2)*2);
  float m = (d > 0.f) ? 1.f : 0.f;
  float a0 = t00.x + fv*(t01.x - t00.x);
  float b0 = t10.x + fv*(t11.x - t10.x);
  out[0] = m * (a0 + fu*(b0 - a0));
  float a1 = t00.y + fv*(t01.y - t00.y);
  float b1v = t10.y + fv*(t11.y - t10.y);
  out[1] = m * (a1 + fu*(b1v - a1));
}

__global__ __launch_bounds__(256) void edge_lookup_kernel(
    const float4* __restrict__ adj2, const float* __restrict__ tab,
    ushort* __restrict__ a_bf)
{
  int e2 = blockIdx.x*256 + threadIdx.x;
  float4 v = adj2[e2];
  float r0[2], r1[2];
  lookup2(tab, v.x, v.y, r0);
  lookup2(tab, v.z, v.w, r1);
  #pragma unroll
  for (int l = 0; l < LL; ++l) {
    ushort2 o;
    o.x = f2bf(r0[l]);
    o.y = f2bf(r1[l]);
    *(ushort2*)&a_bf[(size_t)l*NE + 2*e2] = o;
  }
}

// ---------------- staging helpers (linear LDS dest + pre-swizzled source) ----------------
__device__ __forceinline__ void stage64(const ushort* __restrict__ srcrow0, int stride, int k0,
                                        ushort* dst, int w, int lane)
{
  #pragma unroll
  for (int u = 0; u < 2; ++u) {
    int o = (u*4 + w)*1024 + lane*16;
    int r = o >> 7;
    int c = (o & 127) ^ ((r & 7) << 4);
    const ushort* src = srcrow0 + (size_t)r*stride + k0 + (c >> 1);
    __builtin_amdgcn_global_load_lds(
        (const __attribute__((address_space(1))) unsigned int*)(const void*)src,
        (__attribute__((address_space(3))) unsigned int*)(void*)(dst + (u*4+w)*512),
        16, 0, 0);
  }
}

__device__ __forceinline__ void stage32(const ushort* __restrict__ srcrow0, int stride, int k0,
                                        ushort* dst, int w, int lane)
{
  int o = w*1024 + lane*16;
  int r = o >> 7;                  // 0..31
  int c = (o & 127) ^ ((r & 7) << 4);
  const ushort* src = srcrow0 + (size_t)r*stride + k0 + (c >> 1);
  __builtin_amdgcn_global_load_lds(
      (const __attribute__((address_space(1))) unsigned int*)(const void*)src,
      (__attribute__((address_space(3))) unsigned int*)(void*)(dst + w*512),
      16, 0, 0);
}

// ---------------- G1: xa[n][j] = sum_m a[n][m]*xT[j][m]; 32x64 tile, BK=128, 512 blocks ----------------
__device__ __forceinline__ void compute32x64_bk128(const ushort* sAc, const ushort* sBc,
    int wr, int wc, int lane, f32x4 acc[2])
{
  int kb = (lane >> 4) * 16;
  #pragma unroll
  for (int ks = 0; ks < 4; ++ks) {
    int sub = ks >> 1;
    int inb = (ks & 1)*64 + kb;
    int rA = wr*16 + (lane & 15);
    int offA = (rA*128 + inb) ^ ((rA & 7) << 4);
    bf16x8 af = *(const bf16x8*)((const char*)sAc + sub*4096 + offA);
    #pragma unroll
    for (int nj = 0; nj < 2; ++nj) {
      int rB = wc*32 + nj*16 + (lane & 15);
      int offB = (rB*128 + inb) ^ ((rB & 7) << 4);
      bf16x8 bg = *(const bf16x8*)((const char*)sBc + sub*8192 + offB);
      acc[nj] = __builtin_amdgcn_mfma_f32_16x16x32_bf16(af, bg, acc[nj], 0, 0, 0);
    }
  }
}

// Counted-vmcnt 2-deep pipeline. Safety vs the R5-R7 race class:
//  - every stage GROUP is separated by a compiler fence (asm "" memory), so the
//    per-wave vmem issue order is strictly tile-by-tile -> vmcnt(6) (6 loads/tile/
//    thread) isolates exactly "tile t complete";
//  - lgkmcnt(0)+barrier after compute ensures all waves' LDS reads of buf c are
//    drained before tile t+2 is DMA'd into it (R7 lesson).
__global__ __launch_bounds__(256) void g1_kernel(
    const ushort* __restrict__ A, const ushort* __restrict__ B,
    ushort* __restrict__ C)
{
  __shared__ __align__(16) ushort sA[2][4096];  // [32][128] per buf (8KB)
  __shared__ __align__(16) ushort sB[2][8192];  // [64][128] per buf (16KB)
  int tid = threadIdx.x;
  int w = tid >> 6, lane = tid & 63;
  int tm = blockIdx.x >> 4;     // 0..31
  int tj = blockIdx.x & 15;     // 0..15
  int n0 = tm*32, j0 = tj*64;
  const ushort* Ab = A + (size_t)n0*NP;
  const ushort* Bb = B + (size_t)j0*NP;
  int wr = w >> 1, wc = w & 1;
  f32x4 acc[2] = {};

  // prologue: tiles 0 and 1, strict issue order
  stage32(Ab, NP, 0,   &sA[0][0],    w, lane);
  stage32(Ab, NP, 64,  &sA[0][2048], w, lane);
  stage64(Bb, NP, 0,   &sB[0][0],    w, lane);
  stage64(Bb, NP, 64,  &sB[0][4096], w, lane);
  asm volatile("" ::: "memory");
  stage32(Ab, NP, 128, &sA[1][0],    w, lane);
  stage32(Ab, NP, 192, &sA[1][2048], w, lane);
  stage64(Bb, NP, 128, &sB[1][0],    w, lane);
  stage64(Bb, NP, 192, &sB[1][4096], w, lane);

  #pragma unroll
  for (int t = 0; t < 8; ++t) {
    int c = t & 1;
    if (t < 7) asm volatile("s_waitcnt vmcnt(6)" ::: "memory");  // tile t landed (newest 6 = tile t+1)
    else       asm volatile("s_waitcnt vmcnt(0)" ::: "memory");  // last tile: drain all
    asm volatile("s_barrier" ::: "memory");                      // all waves have tile t
    compute32x64_bk128(&sA[c][0], &sB[c][0], wr, wc, lane, acc);
    asm volatile("s_waitcnt lgkmcnt(0)" ::: "memory");           // this wave's buf-c reads drained
    asm volatile("s_barrier" ::: "memory");                      // all waves done with buf c
    if (t + 2 < 8) {
      int k0 = (t+2)*128;
      stage32(Ab, NP, k0,      &sA[c][0],    w, lane);
      stage32(Ab, NP, k0+64,   &sA[c][2048], w, lane);
      stage64(Bb, NP, k0,      &sB[c][0],    w, lane);
      stage64(Bb, NP, k0+64,   &sB[c][4096], w, lane);
      asm volatile("" ::: "memory");
    }
  }

  int colb = wc*32 + (lane & 15);
  int rowb = wr*16 + ((lane >> 4) << 2);
  #pragma unroll
  for (int nj = 0; nj < 2; ++nj) {
    int j = j0 + colb + nj*16;
    #pragma unroll
    for (int i = 0; i < 4; ++i) {
      int n = n0 + rowb + i;
      C[(size_t)n*NP + j] = f2bf(acc[nj][i]);
    }
  }
}

// ---------------- K2: fused fc-GEMM + bias + skip + LayerNorm + dual output ----------------
// 16-row blocks, 512 blocks.  xh[n][g] = sum_k xa[n][b*128+k]*Wfc[g][k]; y = xh+xin+bias; LN.
template<bool LAST>
__global__ __launch_bounds__(256) void fc_ln_kernel(
    const ushort* __restrict__ xa, const ushort* __restrict__ wl,
    const float* __restrict__ xin, const float* __restrict__ bias_l,
    const float* __restrict__ gamma_l, const float* __restrict__ beta_l,
    float* __restrict__ out, ushort* __restrict__ xT2)
{
  __shared__ __align__(16) char smem[54016];
  ushort* sXA = (ushort*)smem;                        // 4KB: 2 subtiles [16][64] (2048B each)
  ushort* sW  = (ushort*)(smem + 4096);               // 32KB: 4 subtiles [64][64] (8192B each)
  float (*sY)[132] = (float(*)[132])(smem + 36864);   // [16][132] f32 (8448B)
  float (*sXB)[17] = (float(*)[17])(smem + 45312);    // [128][17] f32 (8704B) — no aliasing

  int b  = blockIdx.x >> 6;          // 0..7
  int n0 = (blockIdx.x & 63) * 16;
  int tid = threadIdx.x, w = tid >> 6, lane = tid & 63;

  // stage xa tile [16 n][128 k]: one 16B load per thread
  {
    int kh = tid >> 7;
    int o  = (tid & 127) * 16;
    int r  = o >> 7;                 // 0..15
    int c  = (o & 127) ^ ((r & 7) << 4);
    const ushort* src = xa + (size_t)(n0 + r)*NP + b*FF + kh*64 + (c >> 1);
    __builtin_amdgcn_global_load_lds(
        (const __attribute__((address_space(1))) unsigned int*)(const void*)src,
        (__attribute__((address_space(3))) unsigned int*)(void*)(sXA + w*512),
        16, 0, 0);
  }
  // stage Wfc [128 g][128 k] (4 subtiles, 8192B stride)
  #pragma unroll
  for (int gr = 0; gr < 2; ++gr)
    #pragma unroll
    for (int kf = 0; kf < 2; ++kf)
      stage64(wl + gr*64*FF, FF, kf*64, sW + (gr*2+kf)*4096, w, lane);

  // skip-connection + bias loads (overlap with staging)
  int col = lane & 15;
  int rowb = (lane >> 4) * 4;
  float xr[2][4];
  float bv[2];
  #pragma unroll
  for (int nj = 0; nj < 2; ++nj) {
    int g = w*32 + nj*16 + col;
    bv[nj] = bias_l[g];
    #pragma unroll
    for (int i = 0; i < 4; ++i)
      xr[nj][i] = xin[((size_t)b*NP + n0 + rowb + i)*FF + g];
  }
  __syncthreads();

  // MFMA: C[16 n][128 g], K=128
  f32x4 acc[2] = {};
  #pragma unroll
  for (int ks = 0; ks < 4; ++ks) {
    int inb = (ks & 1)*64 + (lane >> 4)*16;
    int r = lane & 15;
    int offA = (r*128 + inb) ^ ((r & 7) << 4);
    bf16x8 af = *(const bf16x8*)((const char*)sXA + (ks>>1)*2048 + offA);
    #pragma unroll
    for (int nj = 0; nj < 2; ++nj) {
      int gg = w*32 + nj*16 + (lane & 15);
      int gr = gg >> 6, rs = gg & 63;
      int offB = (rs*128 + inb) ^ ((rs & 7) << 4);
      bf16x8 bg = *(const bf16x8*)((const char*)sW + (gr*2 + (ks>>1))*8192 + offB);
      acc[nj] = __builtin_amdgcn_mfma_f32_16x16x32_bf16(af, bg, acc[nj], 0, 0, 0);
    }
  }

  // y -> LDS
  #pragma unroll
  for (int nj = 0; nj < 2; ++nj) {
    int g = w*32 + nj*16 + col;
    #pragma unroll
    for (int i = 0; i < 4; ++i)
      sY[rowb + i][g] = acc[nj][i] + xr[nj][i] + bv[nj];
  }
  __syncthreads();

  // LayerNorm: 16 threads per row
  int row = tid >> 4, seg = tid & 15;
  float4 v[2];
  float s = 0.f, ss = 0.f;
  #pragma unroll
  for (int q = 0; q < 2; ++q) {
    v[q] = *(const float4*)&sY[row][seg*8 + q*4];
    s  += v[q].x + v[q].y + v[q].z + v[q].w;
    ss += v[q].x*v[q].x + v[q].y*v[q].y + v[q].z*v[q].z + v[q].w*v[q].w;
  }
  #pragma unroll
  for (int o = 1; o < 16; o <<= 1) {
    s  += __shfl_xor(s, o);
    ss += __shfl_xor(ss, o);
  }
  float mean = s * (1.f/FF);
  float var  = ss * (1.f/FF) - mean*mean;
  float inv  = __builtin_amdgcn_rsqf(var + 1e-5f);
  size_t obase = ((size_t)b*NP + n0 + row)*FF + seg*8;
  float res[8];
  #pragma unroll
  for (int q = 0; q < 2; ++q) {
    float4 g4 = *(const float4*)&gamma_l[seg*8 + q*4];
    float4 b4 = *(const float4*)&beta_l[seg*8 + q*4];
    float4 o4;
    o4.x = (v[q].x - mean)*inv*g4.x + b4.x;
    o4.y = (v[q].y - mean)*inv*g4.y + b4.y;
    o4.z = (v[q].z - mean)*inv*g4.z + b4.z;
    o4.w = (v[q].w - mean)*inv*g4.w + b4.w;
    *(float4*)&out[obase + q*4] = o4;
    res[q*4+0] = o4.x; res[q*4+1] = o4.y; res[q*4+2] = o4.z; res[q*4+3] = o4.w;
  }

  if constexpr (!LAST) {
    #pragma unroll
    for (int q = 0; q < 8; ++q)
      sXB[seg*8 + q][row] = res[q];
    __syncthreads();
    int f = tid >> 1, half = tid & 1;
    unsigned w0 = (unsigned)f2bf(sXB[f][half*8+0]) | ((unsigned)f2bf(sXB[f][half*8+1])<<16);
    unsigned w1 = (unsigned)f2bf(sXB[f][half*8+2]) | ((unsigned)f2bf(sXB[f][half*8+3])<<16);
    unsigned w2 = (unsigned)f2bf(sXB[f][half*8+4]) | ((unsigned)f2bf(sXB[f][half*8+5])<<16);
    unsigned w3 = (unsigned)f2bf(sXB[f][half*8+6]) | ((unsigned)f2bf(sXB[f][half*8+7])<<16);
    ushort* dst = xT2 + ((size_t)b*FF + f)*NP + n0 + half*8;
    *(uint4*)(dst) = make_uint4(w0, w1, w2, w3);
  }
}

extern "C" void kernel_launch(void* const* d_in, const int* in_sizes, int n_in,
                              void* d_out, int out_size, void* d_ws, size_t ws_size,
                              hipStream_t stream)
{
  const float* x     = (const float*)d_in[0];
  const float* adj   = (const float*)d_in[1];
  const float* W1    = (const float*)d_in[2];
  const float* b1    = (const float*)d_in[3];
  const float* W2    = (const float*)d_in[4];
  const float* b2    = (const float*)d_in[5];
  const float* Wfc   = (const float*)d_in[6];
  const float* bias  = (const float*)d_in[7];
  const float* gamma = (const float*)d_in[8];
  const float* beta  = (const float*)d_in[9];

  float* ws = (float*)d_ws;
  ushort* a_bf  = (ushort*)(ws + 0);        // 2*NE bf16
  ushort* xT    = (ushort*)(ws + 1048576);  // NE bf16
  ushort* xT2   = (ushort*)(ws + 1572864);  // NE bf16
  ushort* xa    = (ushort*)(ws + 2097152);  // NE bf16
  ushort* wfcbf = (ushort*)(ws + 2621440);  // 32768 bf16
  float*  tab   = ws + 2637824;             // TPTS*2 floats (interleaved [p][l])
  float*  xmid  = ws + 2671360;             // NE f32

  pre_kernel<<<292, 256, 0, stream>>>(x, Wfc, W1, b1, W2, b2, xT, wfcbf, tab);
  edge_lookup_kernel<<<NE/512, 256, 0, stream>>>((const float4*)adj, tab, a_bf);

  // layer 0
  g1_kernel<<<512, 256, 0, stream>>>(a_bf, xT, xa);
  fc_ln_kernel<false><<<512, 256, 0, stream>>>(xa, wfcbf, x, bias, gamma, beta, xmid, xT2);
  // layer 1
  g1_kernel<<<512, 256, 0, stream>>>(a_bf + NE, xT2, xa);
  fc_ln_kernel<true><<<512, 256, 0, stream>>>(xa, wfcbf + FF*FF, xmid, bias + FF,
                                              gamma + FF, beta + FF, (float*)d_out, nullptr);
}

// Round 14
// 48.414 us; speedup vs baseline: 8.0981x; 1.0251x over previous
//
#include <hip/hip_runtime.h>

#define LL 2
#define NP 1024
#define BB 8
#define FF 128
#define HH 256
#define NE (NP*NP)
#define GT 128
#define TPTS ((GT+1)*(GT+1))

typedef __attribute__((ext_vector_type(4))) float f32x4;
typedef __attribute__((ext_vector_type(8))) short bf16x8;

__device__ __forceinline__ ushort f2bf(float f) {
  unsigned int u = __float_as_uint(f);
  return (ushort)((u + 0x7FFF + ((u >> 16) & 1)) >> 16);
}

// ---------------- pre: xT transpose (0..127) + Wfc->bf16 (128..159) + table (160..291) ----------------
__global__ __launch_bounds__(256) void pre_kernel(
    const float* __restrict__ x, const float* __restrict__ Wfc,
    const float* __restrict__ W1, const float* __restrict__ b1,
    const float* __restrict__ W2, const float* __restrict__ b2,
    ushort* __restrict__ xT, ushort* __restrict__ wfcbf, float* __restrict__ tab)
{
  __shared__ __align__(16) char smem[18432];
  int t = threadIdx.x;
  int bid = blockIdx.x;

  if (bid >= 160) {               // ---- table branch ----
    float4* spk = (float4*)smem;              // 256 float4
    float*  sred = (float*)(smem + 4096);     // 256 f32
    int q = bid - 160;
    int l = (q >= 66) ? 1 : 0;
    int pb = q - l*66;
    float wx = W1[(l*HH + t)*2 + 0];
    float wy = W1[(l*HH + t)*2 + 1];
    float bb = b1[l*HH + t];
    float w2 = W2[l*HH + t];
    spk[t] = make_float4(wx*1.44269504f, wy*1.44269504f, bb*1.44269504f, w2);
    sred[t] = w2;
    __syncthreads();
    for (int s = 128; s > 0; s >>= 1) {
      if (t < s) sred[t] += sred[t+s];
      __syncthreads();
    }
    float sw2 = sred[0];
    int p = pb*256 + t;
    if (p >= TPTS) return;
    int i = p / (GT+1), j = p % (GT+1);
    float d = i * (1.0f/GT), tt = j * (1.0f/GT);
    float accp = 0.f, acce = 0.f;
    #pragma unroll 8
    for (int k = 0; k < HH; ++k) {
      float4 c = spk[k];
      float z2 = fmaf(d, c.x, fmaf(tt, c.y, c.z));
      accp = fmaf(c.w, fmaxf(z2, 0.f), accp);
      acce = fmaf(c.w, __builtin_amdgcn_exp2f(fminf(z2, 0.f)), acce);
    }
    float s = fmaf(0.69314718f, accp, acce) - sw2 + b2[l];
    float ax = fabsf(s);
    float e2 = __builtin_amdgcn_exp2f(-2.88539008f * ax);
    float r = (1.f - e2) * __builtin_amdgcn_rcpf(1.f + e2);
    tab[p*2 + l] = (s >= 0.f) ? r : -r;
    return;
  }

  if (bid >= 128) {               // ---- Wfc convert branch ----
    int i4 = (bid - 128)*256 + t;
    float4 v = *(const float4*)(Wfc + (size_t)i4*4);
    ushort4 o;
    o.x = f2bf(v.x); o.y = f2bf(v.y); o.z = f2bf(v.z); o.w = f2bf(v.w);
    *(ushort4*)(wfcbf + (size_t)i4*4) = o;
    return;
  }

  // ---- xT transpose branch ----
  ushort (*sT)[72] = (ushort(*)[72])smem;     // [128][72]
  int b = bid >> 4;
  int m0 = (bid & 15) * 64;
  int mr = t >> 2;
  int fc = (t & 3) * 32;
  const float* src = x + ((size_t)b*NP + m0 + mr)*FF + fc;
  #pragma unroll
  for (int i = 0; i < 8; ++i) {
    float4 v = *(const float4*)(src + i*4);
    sT[fc + i*4 + 0][mr] = f2bf(v.x);
    sT[fc + i*4 + 1][mr] = f2bf(v.y);
    sT[fc + i*4 + 2][mr] = f2bf(v.z);
    sT[fc + i*4 + 3][mr] = f2bf(v.w);
  }
  __syncthreads();
  int f = t >> 1, half = t & 1;
  ushort* dst = xT + ((size_t)b*FF + f)*NP + m0 + half*32;
  #pragma unroll
  for (int q = 0; q < 4; ++q)
    *(uint4*)(dst + q*8) = *(const uint4*)&sT[f][half*32 + q*8];
}

// ---------------- edge lookup: bilinear for both layers at once ----------------
__device__ __forceinline__ void lookup2(const float* __restrict__ tab,
                                        float d, float t, float out[2])
{
  float u = d * (float)GT, vv = t * (float)GT;
  int iu = (int)u; iu = min(iu, GT-1);
  int iv = (int)vv; iv = min(iv, GT-1);
  float fu = u - iu, fv = vv - iv;
  const float* p = tab + (size_t)(iu*(GT+1) + iv)*2;
  float2 t00 = *(const float2*)(p);
  float2 t01 = *(const float2*)(p + 2);
  float2 t10 = *(const float2*)(p + (GT+1)*2);
  float2 t11 = *(const float2*)(p + (GT+2)*2);
  float m = (d > 0.f) ? 1.f : 0.f;
  float a0 = t00.x + fv*(t01.x - t00.x);
  float b0 = t10.x + fv*(t11.x - t10.x);
  out[0] = m * (a0 + fu*(b0 - a0));
  float a1 = t00.y + fv*(t01.y - t00.y);
  float b1v = t10.y + fv*(t11.y - t10.y);
  out[1] = m * (a1 + fu*(b1v - a1));
}

__global__ __launch_bounds__(256) void edge_lookup_kernel(
    const float4* __restrict__ adj2, const float* __restrict__ tab,
    ushort* __restrict__ a_bf)
{
  int e2 = blockIdx.x*256 + threadIdx.x;
  float4 v = adj2[e2];
  float r0[2], r1[2];
  lookup2(tab, v.x, v.y, r0);
  lookup2(tab, v.z, v.w, r1);
  #pragma unroll
  for (int l = 0; l < LL; ++l) {
    ushort2 o;
    o.x = f2bf(r0[l]);
    o.y = f2bf(r1[l]);
    *(ushort2*)&a_bf[(size_t)l*NE + 2*e2] = o;
  }
}

// ---------------- staging helpers (linear LDS dest + pre-swizzled source) ----------------
__device__ __forceinline__ void stage64(const ushort* __restrict__ srcrow0, int stride, int k0,
                                        ushort* dst, int w, int lane)
{
  #pragma unroll
  for (int u = 0; u < 2; ++u) {
    int o = (u*4 + w)*1024 + lane*16;
    int r = o >> 7;
    int c = (o & 127) ^ ((r & 7) << 4);
    const ushort* src = srcrow0 + (size_t)r*stride + k0 + (c >> 1);
    __builtin_amdgcn_global_load_lds(
        (const __attribute__((address_space(1))) unsigned int*)(const void*)src,
        (__attribute__((address_space(3))) unsigned int*)(void*)(dst + (u*4+w)*512),
        16, 0, 0);
  }
}

__device__ __forceinline__ void stage32(const ushort* __restrict__ srcrow0, int stride, int k0,
                                        ushort* dst, int w, int lane)
{
  int o = w*1024 + lane*16;
  int r = o >> 7;                  // 0..31
  int c = (o & 127) ^ ((r & 7) << 4);
  const ushort* src = srcrow0 + (size_t)r*stride + k0 + (c >> 1);
  __builtin_amdgcn_global_load_lds(
      (const __attribute__((address_space(1))) unsigned int*)(const void*)src,
      (__attribute__((address_space(3))) unsigned int*)(void*)(dst + w*512),
      16, 0, 0);
}

// ---------------- G1: xa[n][j] = sum_m a[n][m]*xT[j][m]; 32x64 tile, BK=128, 512 blocks ----------------
__device__ __forceinline__ void compute32x64_bk128(const ushort* sAc, const ushort* sBc,
    int wr, int wc, int lane, f32x4 acc[2])
{
  int kb = (lane >> 4) * 16;
  #pragma unroll
  for (int ks = 0; ks < 4; ++ks) {
    int sub = ks >> 1;
    int inb = (ks & 1)*64 + kb;
    int rA = wr*16 + (lane & 15);
    int offA = (rA*128 + inb) ^ ((rA & 7) << 4);
    bf16x8 af = *(const bf16x8*)((const char*)sAc + sub*4096 + offA);
    #pragma unroll
    for (int nj = 0; nj < 2; ++nj) {
      int rB = wc*32 + nj*16 + (lane & 15);
      int offB = (rB*128 + inb) ^ ((rB & 7) << 4);
      bf16x8 bg = *(const bf16x8*)((const char*)sBc + sub*8192 + offB);
      acc[nj] = __builtin_amdgcn_mfma_f32_16x16x32_bf16(af, bg, acc[nj], 0, 0, 0);
    }
  }
}

// 3-buffer rotation, ONE barrier per K-iter. Safety (R13-proven reasoning):
//  - stage groups fence-separated -> strict per-wave issue order -> vmcnt(6)
//    isolates "tile t landed" (6 loads/tile/thread);
//  - combined lgkmcnt(0) before the barrier: all waves' reads of tile t-1
//    drained -> buf[(t+2)%3] (which held tile t-1) is safe to re-stage;
//  - concurrent DMAs target (t+1)%3 and (t+2)%3, never the compute buf t%3;
//  - a buffer's previous DMA completed >=1 iter before it is re-staged.
__global__ __launch_bounds__(256) void g1_kernel(
    const ushort* __restrict__ A, const ushort* __restrict__ B,
    ushort* __restrict__ C)
{
  __shared__ __align__(16) ushort sA[3][4096];  // [32][128] per buf (8KB) x3
  __shared__ __align__(16) ushort sB[3][8192];  // [64][128] per buf (16KB) x3 -> 72KB
  int tid = threadIdx.x;
  int w = tid >> 6, lane = tid & 63;
  // XCD-contiguous remap (bijective: 512 % 8 == 0): each XCD gets 4 A-panels +
  // all B-panels = 2.25MB, fits its 4MB L2 (vs ~4MB thrash round-robin).
  int bid = ((blockIdx.x & 7) << 6) | (blockIdx.x >> 3);
  int tm = bid >> 4;            // 0..31
  int tj = bid & 15;            // 0..15
  int n0 = tm*32, j0 = tj*64;
  const ushort* Ab = A + (size_t)n0*NP;
  const ushort* Bb = B + (size_t)j0*NP;
  int wr = w >> 1, wc = w & 1;
  f32x4 acc[2] = {};

  // prologue: tiles 0 and 1, strict issue order
  stage32(Ab, NP, 0,   &sA[0][0],    w, lane);
  stage32(Ab, NP, 64,  &sA[0][2048], w, lane);
  stage64(Bb, NP, 0,   &sB[0][0],    w, lane);
  stage64(Bb, NP, 64,  &sB[0][4096], w, lane);
  asm volatile("" ::: "memory");
  stage32(Ab, NP, 128, &sA[1][0],    w, lane);
  stage32(Ab, NP, 192, &sA[1][2048], w, lane);
  stage64(Bb, NP, 128, &sB[1][0],    w, lane);
  stage64(Bb, NP, 192, &sB[1][4096], w, lane);
  asm volatile("" ::: "memory");

  #pragma unroll
  for (int t = 0; t < 8; ++t) {
    int c = t % 3;
    if (t < 7) asm volatile("s_waitcnt vmcnt(6) lgkmcnt(0)\n\ts_barrier" ::: "memory");
    else       asm volatile("s_waitcnt vmcnt(0) lgkmcnt(0)\n\ts_barrier" ::: "memory");
    if (t + 2 < 8) {
      int k0 = (t+2)*128;
      int cn = (t+2) % 3;
      stage32(Ab, NP, k0,      &sA[cn][0],    w, lane);
      stage32(Ab, NP, k0+64,   &sA[cn][2048], w, lane);
      stage64(Bb, NP, k0,      &sB[cn][0],    w, lane);
      stage64(Bb, NP, k0+64,   &sB[cn][4096], w, lane);
      asm volatile("" ::: "memory");
    }
    compute32x64_bk128(&sA[c][0], &sB[c][0], wr, wc, lane, acc);
  }

  int colb = wc*32 + (lane & 15);
  int rowb = wr*16 + ((lane >> 4) << 2);
  #pragma unroll
  for (int nj = 0; nj < 2; ++nj) {
    int j = j0 + colb + nj*16;
    #pragma unroll
    for (int i = 0; i < 4; ++i) {
      int n = n0 + rowb + i;
      C[(size_t)n*NP + j] = f2bf(acc[nj][i]);
    }
  }
}

// ---------------- K2: fused fc-GEMM + bias + skip + LayerNorm + dual output ----------------
// 16-row blocks, 512 blocks.  xh[n][g] = sum_k xa[n][b*128+k]*Wfc[g][k]; y = xh+xin+bias; LN.
template<bool LAST>
__global__ __launch_bounds__(256) void fc_ln_kernel(
    const ushort* __restrict__ xa, const ushort* __restrict__ wl,
    const float* __restrict__ xin, const float* __restrict__ bias_l,
    const float* __restrict__ gamma_l, const float* __restrict__ beta_l,
    float* __restrict__ out, ushort* __restrict__ xT2)
{
  __shared__ __align__(16) char smem[54016];
  ushort* sXA = (ushort*)smem;                        // 4KB: 2 subtiles [16][64] (2048B each)
  ushort* sW  = (ushort*)(smem + 4096);               // 32KB: 4 subtiles [64][64] (8192B each)
  float (*sY)[132] = (float(*)[132])(smem + 36864);   // [16][132] f32 (8448B)
  float (*sXB)[17] = (float(*)[17])(smem + 45312);    // [128][17] f32 (8704B) — no aliasing

  int b  = blockIdx.x >> 6;          // 0..7
  int n0 = (blockIdx.x & 63) * 16;
  int tid = threadIdx.x, w = tid >> 6, lane = tid & 63;

  // stage xa tile [16 n][128 k]: one 16B load per thread
  {
    int kh = tid >> 7;
    int o  = (tid & 127) * 16;
    int r  = o >> 7;                 // 0..15
    int c  = (o & 127) ^ ((r & 7) << 4);
    const ushort* src = xa + (size_t)(n0 + r)*NP + b*FF + kh*64 + (c >> 1);
    __builtin_amdgcn_global_load_lds(
        (const __attribute__((address_space(1))) unsigned int*)(const void*)src,
        (__attribute__((address_space(3))) unsigned int*)(void*)(sXA + w*512),
        16, 0, 0);
  }
  // stage Wfc [128 g][128 k] (4 subtiles, 8192B stride)
  #pragma unroll
  for (int gr = 0; gr < 2; ++gr)
    #pragma unroll
    for (int kf = 0; kf < 2; ++kf)
      stage64(wl + gr*64*FF, FF, kf*64, sW + (gr*2+kf)*4096, w, lane);

  // skip-connection + bias loads (overlap with staging)
  int col = lane & 15;
  int rowb = (lane >> 4) * 4;
  float xr[2][4];
  float bv[2];
  #pragma unroll
  for (int nj = 0; nj < 2; ++nj) {
    int g = w*32 + nj*16 + col;
    bv[nj] = bias_l[g];
    #pragma unroll
    for (int i = 0; i < 4; ++i)
      xr[nj][i] = xin[((size_t)b*NP + n0 + rowb + i)*FF + g];
  }
  __syncthreads();

  // MFMA: C[16 n][128 g], K=128
  f32x4 acc[2] = {};
  #pragma unroll
  for (int ks = 0; ks < 4; ++ks) {
    int inb = (ks & 1)*64 + (lane >> 4)*16;
    int r = lane & 15;
    int offA = (r*128 + inb) ^ ((r & 7) << 4);
    bf16x8 af = *(const bf16x8*)((const char*)sXA + (ks>>1)*2048 + offA);
    #pragma unroll
    for (int nj = 0; nj < 2; ++nj) {
      int gg = w*32 + nj*16 + (lane & 15);
      int gr = gg >> 6, rs = gg & 63;
      int offB = (rs*128 + inb) ^ ((rs & 7) << 4);
      bf16x8 bg = *(const bf16x8*)((const char*)sW + (gr*2 + (ks>>1))*8192 + offB);
      acc[nj] = __builtin_amdgcn_mfma_f32_16x16x32_bf16(af, bg, acc[nj], 0, 0, 0);
    }
  }

  // y -> LDS
  #pragma unroll
  for (int nj = 0; nj < 2; ++nj) {
    int g = w*32 + nj*16 + col;
    #pragma unroll
    for (int i = 0; i < 4; ++i)
      sY[rowb + i][g] = acc[nj][i] + xr[nj][i] + bv[nj];
  }
  __syncthreads();

  // LayerNorm: 16 threads per row
  int row = tid >> 4, seg = tid & 15;
  float4 v[2];
  float s = 0.f, ss = 0.f;
  #pragma unroll
  for (int q = 0; q < 2; ++q) {
    v[q] = *(const float4*)&sY[row][seg*8 + q*4];
    s  += v[q].x + v[q].y + v[q].z + v[q].w;
    ss += v[q].x*v[q].x + v[q].y*v[q].y + v[q].z*v[q].z + v[q].w*v[q].w;
  }
  #pragma unroll
  for (int o = 1; o < 16; o <<= 1) {
    s  += __shfl_xor(s, o);
    ss += __shfl_xor(ss, o);
  }
  float mean = s * (1.f/FF);
  float var  = ss * (1.f/FF) - mean*mean;
  float inv  = __builtin_amdgcn_rsqf(var + 1e-5f);
  size_t obase = ((size_t)b*NP + n0 + row)*FF + seg*8;
  float res[8];
  #pragma unroll
  for (int q = 0; q < 2; ++q) {
    float4 g4 = *(const float4*)&gamma_l[seg*8 + q*4];
    float4 b4 = *(const float4*)&beta_l[seg*8 + q*4];
    float4 o4;
    o4.x = (v[q].x - mean)*inv*g4.x + b4.x;
    o4.y = (v[q].y - mean)*inv*g4.y + b4.y;
    o4.z = (v[q].z - mean)*inv*g4.z + b4.z;
    o4.w = (v[q].w - mean)*inv*g4.w + b4.w;
    *(float4*)&out[obase + q*4] = o4;
    res[q*4+0] = o4.x; res[q*4+1] = o4.y; res[q*4+2] = o4.z; res[q*4+3] = o4.w;
  }

  if constexpr (!LAST) {
    #pragma unroll
    for (int q = 0; q < 8; ++q)
      sXB[seg*8 + q][row] = res[q];
    __syncthreads();
    int f = tid >> 1, half = tid & 1;
    unsigned w0 = (unsigned)f2bf(sXB[f][half*8+0]) | ((unsigned)f2bf(sXB[f][half*8+1])<<16);
    unsigned w1 = (unsigned)f2bf(sXB[f][half*8+2]) | ((unsigned)f2bf(sXB[f][half*8+3])<<16);
    unsigned w2 = (unsigned)f2bf(sXB[f][half*8+4]) | ((unsigned)f2bf(sXB[f][half*8+5])<<16);
    unsigned w3 = (unsigned)f2bf(sXB[f][half*8+6]) | ((unsigned)f2bf(sXB[f][half*8+7])<<16);
    ushort* dst = xT2 + ((size_t)b*FF + f)*NP + n0 + half*8;
    *(uint4*)(dst) = make_uint4(w0, w1, w2, w3);
  }
}

extern "C" void kernel_launch(void* const* d_in, const int* in_sizes, int n_in,
                              void* d_out, int out_size, void* d_ws, size_t ws_size,
                              hipStream_t stream)
{
  const float* x     = (const float*)d_in[0];
  const float* adj   = (const float*)d_in[1];
  const float* W1    = (const float*)d_in[2];
  const float* b1    = (const float*)d_in[3];
  const float* W2    = (const float*)d_in[4];
  const float* b2    = (const float*)d_in[5];
  const float* Wfc   = (const float*)d_in[6];
  const float* bias  = (const float*)d_in[7];
  const float* gamma = (const float*)d_in[8];
  const float* beta  = (const float*)d_in[9];

  float* ws = (float*)d_ws;
  ushort* a_bf  = (ushort*)(ws + 0);        // 2*NE bf16
  ushort* xT    = (ushort*)(ws + 1048576);  // NE bf16
  ushort* xT2   = (ushort*)(ws + 1572864);  // NE bf16
  ushort* xa    = (ushort*)(ws + 2097152);  // NE bf16
  ushort* wfcbf = (ushort*)(ws + 2621440);  // 32768 bf16
  float*  tab   = ws + 2637824;             // TPTS*2 floats (interleaved [p][l])
  float*  xmid  = ws + 2671360;             // NE f32

  pre_kernel<<<292, 256, 0, stream>>>(x, Wfc, W1, b1, W2, b2, xT, wfcbf, tab);
  edge_lookup_kernel<<<NE/512, 256, 0, stream>>>((const float4*)adj, tab, a_bf);

  // layer 0
  g1_kernel<<<512, 256, 0, stream>>>(a_bf, xT, xa);
  fc_ln_kernel<false><<<512, 256, 0, stream>>>(xa, wfcbf, x, bias, gamma, beta, xmid, xT2);
  // layer 1
  g1_kernel<<<512, 256, 0, stream>>>(a_bf + NE, xT2, xa);
  fc_ln_kernel<true><<<512, 256, 0, stream>>>(xa, wfcbf + FF*FF, xmid, bias + FF,
                                              gamma + FF, beta + FF, (float*)d_out, nullptr);
}